// Round 2
// baseline (173.197 us; speedup 1.0000x reference)
//
#include <hip/hip_runtime.h>

#define B_    2
#define N_TOK 2048
#define C_    1024
#define H_    16
#define D_    64
#define M_    (B_*N_TOK)   // 4096
#define N3C   3072

typedef unsigned short u16;
typedef unsigned int   u32;

typedef __attribute__((ext_vector_type(8))) short bf16x8;
typedef __attribute__((ext_vector_type(4))) float f32x4;

__device__ __forceinline__ u16 f2bf(float f) {       // RNE
  u32 u = __float_as_uint(f);
  return (u16)((u + 0x7FFFu + ((u >> 16) & 1u)) >> 16);
}
__device__ __forceinline__ u16 f2bf_fast(float f) {  // round-half-up (P only)
  return (u16)((__float_as_uint(f) + 0x8000u) >> 16);
}

// async global->LDS, 16B/lane; LDS dest = wave-uniform base + lane*16
__device__ __forceinline__ void async16(const u16* g, u16* l) {
  __builtin_amdgcn_global_load_lds(
      (const __attribute__((address_space(1))) u32*)g,
      (__attribute__((address_space(3))) u32*)l, 16, 0, 0);
}

// ---------------- fused fp32 -> bf16 convert ----------------
__global__ void k_cvt(const float* __restrict__ x, const float* __restrict__ wq,
                      const float* __restrict__ wo,
                      u16* __restrict__ xb, u16* __restrict__ wqb, u16* __restrict__ wob) {
  size_t i = ((size_t)blockIdx.x * 256 + threadIdx.x) * 4;
  const size_t n0 = (size_t)M_ * C_;
  const size_t n1 = n0 + (size_t)N3C * C_;
  const float* s; u16* d;
  if (i < n0)      { s = x  + i;        d = xb  + i; }
  else if (i < n1) { s = wq + (i - n0); d = wqb + (i - n0); }
  else             { s = wo + (i - n1); d = wob + (i - n1); }
  float4 v = *(const float4*)s;
  *(ushort4*)d = make_ushort4(f2bf(v.x), f2bf(v.y), f2bf(v.z), f2bf(v.w));
}

// ---------------- GEMM1: qkv = x @ w_qkv^T + b   (BK=64, swizzled staging) ----------------
// Q -> [B,H,N,D] pre-scaled by 0.125*log2(e).
// K -> blocked [bh][t32:64][c:8][row:32][e:8], rows PERMUTED: key w at row
//      p(w) = ((w>>2)&1)*16 + ((w>>3)&3)*4 + (w&3)  (makes S^T C-layout == K=32 A-frag).
// V -> [b,h,d,N], key-chunks XOR-swizzled: chunk' = ((t>>3)&7) ^ (d&7).
__global__ __launch_bounds__(256, 3) void k_gemm_qkv(
    const u16* __restrict__ A, const u16* __restrict__ Bm,
    const float* __restrict__ bias,
    u16* __restrict__ qout, u16* __restrict__ kout, u16* __restrict__ vout)
{
  __shared__ u16 As[128*64];   // 16 KB
  __shared__ u16 Bs[128*64];   // 16 KB
  const int K = C_;
  int bm = blockIdx.x, bn = blockIdx.y;
  int tid = threadIdx.x;
  int lane = tid & 63, wave = tid >> 6;
  int wrow = (wave >> 1) * 64, wcol = (wave & 1) * 64;
  int qd = lane >> 4, ln = lane & 15;

  f32x4 zero = {0.f, 0.f, 0.f, 0.f};
  f32x4 acc[4][4];
  for (int i = 0; i < 4; i++) for (int j = 0; j < 4; j++) acc[i][j] = zero;

  const u16* Ab = A  + (size_t)bm * 128 * K;
  const u16* Bb = Bm + (size_t)bn * 128 * K;

  for (int k0 = 0; k0 < K; k0 += 64) {
    __syncthreads();
    for (int j = 0; j < 4; j++) {
      int slot = (wave*4 + j)*64 + lane;
      int r = slot >> 3, kc = slot & 7;
      int c = (kc ^ (r & 7)) * 8;          // XOR swizzle (LDS dest is forced contiguous)
      async16(&Ab[(size_t)r * K + k0 + c], &As[(wave*4 + j) * 512]);
      async16(&Bb[(size_t)r * K + k0 + c], &Bs[(wave*4 + j) * 512]);
    }
    __syncthreads();
    for (int kk2 = 0; kk2 < 2; kk2++) {
      bf16x8 af[4], bfr[4];
      for (int mi = 0; mi < 4; mi++) {
        int row = wrow + mi*16 + ln;
        af[mi] = *(const bf16x8*)&As[(row*8 + ((kk2*4 + qd) ^ (ln & 7)))*8];
      }
      for (int ni = 0; ni < 4; ni++) {
        int row = wcol + ni*16 + ln;
        bfr[ni] = *(const bf16x8*)&Bs[(row*8 + ((kk2*4 + qd) ^ (ln & 7)))*8];
      }
      for (int mi = 0; mi < 4; mi++)
        for (int ni = 0; ni < 4; ni++)
          acc[mi][ni] = __builtin_amdgcn_mfma_f32_16x16x32_bf16(af[mi], bfr[ni], acc[mi][ni], 0, 0, 0);
    }
  }

  for (int ni = 0; ni < 4; ni++) {
    int nbase = bn*128 + wcol + ni*16 + ln;
    int three = nbase >> 10;        // wave-uniform
    int h = (nbase >> 6) & 15;
    int d = nbase & 63;
    float bv = bias[nbase];
    if (three == 2) {
      // V: [b,h,d,N] with XOR'd key chunks; 4 consecutive keys -> one 8B store
      for (int mi = 0; mi < 4; mi++) {
        int row0 = bm*128 + wrow + mi*16 + qd*4;
        int b = row0 >> 11, t0 = row0 & 2047;
        int chunkp = ((t0 >> 3) & 7) ^ (d & 7);
        u16 tmp[4];
        for (int r = 0; r < 4; r++) tmp[r] = f2bf(acc[mi][ni][r] + bv);
        size_t off = ((size_t)(b*H_ + h)*D_ + d)*N_TOK + (t0 >> 6)*64 + chunkp*8 + (t0 & 7);
        *(ushort4*)&vout[off] = *(ushort4*)tmp;
      }
    } else if (three == 1) {
      // K blocked, rows permuted by p(w)
      int c = d >> 3, e = d & 7;
      for (int mi = 0; mi < 4; mi++) {
        for (int r = 0; r < 4; r++) {
          int row = bm*128 + wrow + mi*16 + qd*4 + r;
          int b = row >> 11, t = row & 2047;
          int t32 = t >> 5, w = t & 31;
          int p = ((w >> 2) & 1)*16 + ((w >> 3) & 3)*4 + (w & 3);
          kout[((size_t)(b*H_ + h)*64 + t32)*2048 + (c*32 + p)*8 + e] = f2bf(acc[mi][ni][r] + bv);
        }
      }
    } else {
      float sc = 0.18033688011f;  // 0.125*log2(e) folded into Q
      for (int mi = 0; mi < 4; mi++) {
        for (int r = 0; r < 4; r++) {
          int row = bm*128 + wrow + mi*16 + qd*4 + r;
          int b = row >> 11, t = row & 2047;
          qout[(((size_t)(b*H_ + h))*N_TOK + t)*D_ + d] = f2bf((acc[mi][ni][r] + bv) * sc);
        }
      }
    }
  }
}

// ---------------- flash attention: T14 reg-staged pipeline, single LDS buffer ----------------
// block = 4 waves x 32 q-rows = 128 rows; grid 512 (XCD-swizzled) -> 2 blocks/CU.
// Per tile t: issue global->REG loads for t+1 (compiler emits counted vmcnt at the
// ds_write -- no LDS-alias conservatism), raw barrier, ds_write regs(t), lgkmcnt(0),
// raw barrier, compute(t). Global latency hides under compute; no vmcnt(0) drain.
__global__ __launch_bounds__(256, 2) void k_attn(
    const u16* __restrict__ Q, const u16* __restrict__ Kb, const u16* __restrict__ Vb,
    u16* __restrict__ Oa)   // [B*N][C] bf16
{
  __shared__ __align__(16) u16 Ks[4096];   // two 32-key tiles: [pair:2][c:8][row:32][e:8]
  __shared__ __align__(16) u16 Vs[4096];   // [d:64][chunk':8][e:8], chunk' = kc ^ (d&7)
  int ord = blockIdx.x;                 // 0..511
  int xcd = ord & 7, kk = ord >> 3;
  int bh = xcd * 4 + (kk & 3);          // 4 heads per XCD -> K/V L2-resident
  int qt = kk >> 2;                     // 0..15
  int b = bh >> 4, h = bh & 15;
  int tid = threadIdx.x, lane = tid & 63, wave = tid >> 6;
  int qd = lane >> 4, ln = lane & 15;

  const u16* Qg = Q  + ((size_t)bh * N_TOK + qt*128 + wave*32) * D_;
  const u16* Kg = Kb + (size_t)bh * 64 * 2048;
  const u16* Vg = Vb + (size_t)bh * (size_t)D_ * N_TOK;

  bf16x8 qf[2][2];
  for (int mi = 0; mi < 2; mi++)
    for (int ks = 0; ks < 2; ks++)
      qf[mi][ks] = *(const bf16x8*)&Qg[(mi*16 + ln)*D_ + ks*32 + qd*8];

  f32x4 z = {0.f, 0.f, 0.f, 0.f};
  f32x4 oacc[2][4];
  float lsum[2] = {0.f, 0.f};
  for (int mi = 0; mi < 2; mi++) for (int di = 0; di < 4; di++) oacc[mi][di] = z;

  // per-thread staging slots (identical to the old async16 mapping)
  int cc0 = wave*64 + lane;
  int cc1 = cc0 + 256;
  const u16* Vsrc0 = Vg + (size_t)(cc0 >> 3)*N_TOK + (cc0 & 7)*8;
  const u16* Vsrc1 = Vg + (size_t)(cc1 >> 3)*N_TOK + (cc1 & 7)*8;

  float4 rKA0, rKA1, rVA0, rVA1;   // named reg sets (no runtime indexing -> no scratch)
  float4 rKB0, rKB1, rVB0, rVB1;

  // prologue: tile 0 -> set A
  {
    const u16* Kt = Kg;
    rKA0 = *(const float4*)&Kt[cc0*8];
    rKA1 = *(const float4*)&Kt[cc1*8];
    rVA0 = *(const float4*)&Vsrc0[0];
    rVA1 = *(const float4*)&Vsrc1[0];
  }

  auto body = [&](int kt, float4& cK0, float4& cK1, float4& cV0, float4& cV1,
                  float4& nK0, float4& nK1, float4& nV0, float4& nV1) {
    // issue next tile's global loads into the other reg set (flies under compute)
    if (kt + 1 < 32) {
      const u16* Kt = Kg + (size_t)(kt + 1) * 4096;
      nK0 = *(const float4*)&Kt[cc0*8];
      nK1 = *(const float4*)&Kt[cc1*8];
      nV0 = *(const float4*)&Vsrc0[(size_t)(kt + 1) * 64];
      nV1 = *(const float4*)&Vsrc1[(size_t)(kt + 1) * 64];
    }
    __builtin_amdgcn_sched_barrier(0);
    __builtin_amdgcn_s_barrier();          // all waves done READING prev tile
    __builtin_amdgcn_sched_barrier(0);
    // write current tile (compiler inserts counted vmcnt for cK/cV regs)
    *(float4*)&Ks[cc0*8] = cK0;
    *(float4*)&Ks[cc1*8] = cK1;
    *(float4*)&Vs[cc0*8] = cV0;
    *(float4*)&Vs[cc1*8] = cV1;
    asm volatile("s_waitcnt lgkmcnt(0)" ::: "memory");
    __builtin_amdgcn_sched_barrier(0);
    __builtin_amdgcn_s_barrier();          // tile kt visible to all waves
    __builtin_amdgcn_sched_barrier(0);

    bf16x8 kf[4][2];
    for (int nt = 0; nt < 4; nt++)
      for (int ksd = 0; ksd < 2; ksd++)
        kf[nt][ksd] = *(const bf16x8*)&Ks[(nt>>1)*2048 + ((ksd*4 + qd)*32 + (nt&1)*16 + ln)*8];
    bf16x8 vf[4][2];
    for (int di = 0; di < 4; di++)
      for (int hf = 0; hf < 2; hf++) {
        int d = di*16 + ln;
        vf[di][hf] = *(const bf16x8*)&Vs[(d*8 + ((hf*4 + qd) ^ (ln & 7)))*8];
      }

    // S^T: rows = permuted key positions; sacc[mi][nt][r] at lane qd = key qd*8+(nt&1)*4+r of half nt>>1
    f32x4 sacc[2][4];
    for (int mi = 0; mi < 2; mi++)
      for (int nt = 0; nt < 4; nt++) {
        sacc[mi][nt] = z;
        for (int ksd = 0; ksd < 2; ksd++)
          sacc[mi][nt] = __builtin_amdgcn_mfma_f32_16x16x32_bf16(kf[nt][ksd], qf[mi][ksd], sacc[mi][nt], 0, 0, 0);
      }

    // P = exp2(S'); two f32x4 -> one K=32 A-frag; PV with half the MFMA count
    for (int mi = 0; mi < 2; mi++)
      for (int hf = 0; hf < 2; hf++) {
        union { u16 s[8]; bf16x8 v; } pk;
        for (int nth = 0; nth < 2; nth++)
          for (int i = 0; i < 4; i++) {
            float e = __builtin_amdgcn_exp2f(sacc[mi][hf*2 + nth][i]);
            lsum[mi] += e;
            pk.s[nth*4 + i] = f2bf_fast(e);
          }
        for (int di = 0; di < 4; di++)
          oacc[mi][di] = __builtin_amdgcn_mfma_f32_16x16x32_bf16(pk.v, vf[di][hf], oacc[mi][di], 0, 0, 0);
      }
  };

  for (int kt = 0; kt < 32; kt += 2) {
    body(kt,     rKA0, rKA1, rVA0, rVA1,  rKB0, rKB1, rVB0, rVB1);
    body(kt + 1, rKB0, rKB1, rVB0, rVB1,  rKA0, rKA1, rVA0, rVA1);
  }

  for (int mi = 0; mi < 2; mi++) {
    float ls = lsum[mi];
    ls += __shfl_xor(ls, 16, 64);
    ls += __shfl_xor(ls, 32, 64);
    float rl[4];
    for (int r = 0; r < 4; r++)
      rl[r] = 1.0f / __shfl(ls, qd*4 + r, 64);
    for (int di = 0; di < 4; di++)
      for (int r = 0; r < 4; r++) {
        int t = qt*128 + wave*32 + mi*16 + qd*4 + r;
        Oa[((size_t)b*N_TOK + t)*C_ + h*D_ + di*16 + ln] = f2bf(oacc[mi][di][r] * rl[r]);
      }
  }
}

// ---------------- GEMM2: out = attn @ w_out^T + b_out (fp32 out) ----------------
// 64x128 tile (grid 64x8=512 -> 2 blocks/CU), BK=64, XOR-swizzled staging/read
// (old linear layout was an 8-way ds_read bank conflict), double-buffered LDS,
// single barrier per K-step with issue-early staging.
__global__ __launch_bounds__(256, 2) void k_gemm_out(
    const u16* __restrict__ A, const u16* __restrict__ Bm,
    const float* __restrict__ bias, float* __restrict__ out)
{
  __shared__ u16 As[2][64*64];    // 8 KB x2
  __shared__ u16 Bs[2][128*64];   // 16 KB x2
  const int K = C_;
  int bm = blockIdx.x, bn = blockIdx.y;
  int tid = threadIdx.x;
  int lane = tid & 63, wave = tid >> 6;
  int wcol = wave * 32;
  int qd = lane >> 4, ln = lane & 15;

  f32x4 zero = {0.f, 0.f, 0.f, 0.f};
  f32x4 acc[4][2];
  for (int i = 0; i < 4; i++) for (int j = 0; j < 2; j++) acc[i][j] = zero;

  const u16* Ab = A  + (size_t)bm * 64 * K;
  const u16* Bb = Bm + (size_t)bn * 128 * K;

  auto stage = [&](int buf, int k0) {
    for (int j = 0; j < 2; j++) {            // A: 64x64 = 512 slots of 16B
      int slot = (wave*2 + j)*64 + lane;
      int r = slot >> 3, kc = slot & 7;
      int c = (kc ^ (r & 7)) * 8;            // XOR swizzle
      async16(&Ab[(size_t)r * K + k0 + c], &As[buf][(wave*2 + j) * 512]);
    }
    for (int j = 0; j < 4; j++) {            // B: 128x64 = 1024 slots
      int slot = (wave*4 + j)*64 + lane;
      int r = slot >> 3, kc = slot & 7;
      int c = (kc ^ (r & 7)) * 8;
      async16(&Bb[(size_t)r * K + k0 + c], &Bs[buf][(wave*4 + j) * 512]);
    }
  };

  stage(0, 0);
  __syncthreads();

  for (int t = 0; t < K/64; t++) {
    int cur = t & 1;
    if (t < K/64 - 1) stage(cur ^ 1, (t+1)*64);   // prefetch flies under MFMAs
    for (int kk2 = 0; kk2 < 2; kk2++) {
      bf16x8 af[4], bfr[2];
      for (int mi = 0; mi < 4; mi++) {
        int row = mi*16 + ln;
        af[mi] = *(const bf16x8*)&As[cur][(row*8 + ((kk2*4 + qd) ^ (ln & 7)))*8];
      }
      for (int ni = 0; ni < 2; ni++) {
        int row = wcol + ni*16 + ln;
        bfr[ni] = *(const bf16x8*)&Bs[cur][(row*8 + ((kk2*4 + qd) ^ (ln & 7)))*8];
      }
      for (int mi = 0; mi < 4; mi++)
        for (int ni = 0; ni < 2; ni++)
          acc[mi][ni] = __builtin_amdgcn_mfma_f32_16x16x32_bf16(af[mi], bfr[ni], acc[mi][ni], 0, 0, 0);
    }
    __syncthreads();
  }

  for (int ni = 0; ni < 2; ni++) {
    int col = bn*128 + wcol + ni*16 + ln;
    float bv = bias[col];
    for (int mi = 0; mi < 4; mi++)
      for (int r = 0; r < 4; r++) {
        int row = bm*64 + mi*16 + qd*4 + r;
        out[(size_t)row * C_ + col] = acc[mi][ni][r] + bv;
      }
  }
}

extern "C" void kernel_launch(void* const* d_in, const int* in_sizes, int n_in,
                              void* d_out, int out_size, void* d_ws, size_t ws_size,
                              hipStream_t stream) {
  const float* x     = (const float*)d_in[0];
  const float* w_qkv = (const float*)d_in[1];
  const float* b_qkv = (const float*)d_in[2];
  const float* w_out = (const float*)d_in[3];
  const float* b_out = (const float*)d_in[4];
  float* out = (float*)d_out;

  char* ws = (char*)d_ws;
  u16* x_bf    = (u16*)(ws);
  u16* wqkv_bf = (u16*)(ws + (size_t)8*1024*1024);
  u16* wout_bf = (u16*)(ws + (size_t)14*1024*1024);
  u16* q_bf    = (u16*)(ws + (size_t)16*1024*1024);  // [B,H,N,D], pre-scaled
  u16* k_bf    = (u16*)(ws + (size_t)24*1024*1024);  // blocked, rows permuted
  u16* v_bf    = (u16*)(ws + (size_t)32*1024*1024);  // [b,h,d,N], chunks XOR-swizzled
  u16* a_bf    = (u16*)(ws + (size_t)40*1024*1024);  // [M][C]

  k_cvt<<<8192, 256, 0, stream>>>(x, w_qkv, w_out, x_bf, wqkv_bf, wout_bf);
  k_gemm_qkv<<<dim3(32, 24), 256, 0, stream>>>(x_bf, wqkv_bf, b_qkv, q_bf, k_bf, v_bf);
  k_attn<<<512, 256, 0, stream>>>(q_bf, k_bf, v_bf, a_bf);
  k_gemm_out<<<dim3(64, 8), 256, 0, stream>>>(a_bf, wout_bf, b_out, out);
}

// Round 3
// 170.627 us; speedup vs baseline: 1.0151x; 1.0151x over previous
//
#include <hip/hip_runtime.h>

#define B_    2
#define N_TOK 2048
#define C_    1024
#define H_    16
#define D_    64
#define M_    (B_*N_TOK)   // 4096
#define N3C   3072

typedef unsigned short u16;
typedef unsigned int   u32;

typedef __attribute__((ext_vector_type(8))) short bf16x8;
typedef __attribute__((ext_vector_type(4))) float f32x4;

__device__ __forceinline__ u16 f2bf(float f) {       // RNE
  u32 u = __float_as_uint(f);
  return (u16)((u + 0x7FFFu + ((u >> 16) & 1u)) >> 16);
}
__device__ __forceinline__ u16 f2bf_fast(float f) {  // round-half-up (P only)
  return (u16)((__float_as_uint(f) + 0x8000u) >> 16);
}

// async global->LDS, 16B/lane; LDS dest = wave-uniform base + lane*16
__device__ __forceinline__ void async16(const u16* g, u16* l) {
  __builtin_amdgcn_global_load_lds(
      (const __attribute__((address_space(1))) u32*)g,
      (__attribute__((address_space(3))) u32*)l, 16, 0, 0);
}

// ---------------- fused fp32 -> bf16 convert ----------------
__global__ void k_cvt(const float* __restrict__ x, const float* __restrict__ wq,
                      const float* __restrict__ wo,
                      u16* __restrict__ xb, u16* __restrict__ wqb, u16* __restrict__ wob) {
  size_t i = ((size_t)blockIdx.x * 256 + threadIdx.x) * 4;
  const size_t n0 = (size_t)M_ * C_;
  const size_t n1 = n0 + (size_t)N3C * C_;
  const float* s; u16* d;
  if (i < n0)      { s = x  + i;        d = xb  + i; }
  else if (i < n1) { s = wq + (i - n0); d = wqb + (i - n0); }
  else             { s = wo + (i - n1); d = wob + (i - n1); }
  float4 v = *(const float4*)s;
  *(ushort4*)d = make_ushort4(f2bf(v.x), f2bf(v.y), f2bf(v.z), f2bf(v.w));
}

// ---------------- GEMM1: qkv = x @ w_qkv^T + b   (BK=64, swizzled staging) ----------------
// Q -> [B,H,N,D] pre-scaled by 0.125*log2(e).
// K -> blocked [bh][t32:64][c:8][row:32][e:8], rows PERMUTED: key w at row
//      p(w) = ((w>>2)&1)*16 + ((w>>3)&3)*4 + (w&3)  (makes S^T C-layout == K=32 A-frag).
// V -> [b,h,d,N], key-chunks XOR-swizzled: chunk' = ((t>>3)&7) ^ (d&7).
__global__ __launch_bounds__(256, 3) void k_gemm_qkv(
    const u16* __restrict__ A, const u16* __restrict__ Bm,
    const float* __restrict__ bias,
    u16* __restrict__ qout, u16* __restrict__ kout, u16* __restrict__ vout)
{
  __shared__ u16 As[128*64];   // 16 KB
  __shared__ u16 Bs[128*64];   // 16 KB
  const int K = C_;
  int bm = blockIdx.x, bn = blockIdx.y;
  int tid = threadIdx.x;
  int lane = tid & 63, wave = tid >> 6;
  int wrow = (wave >> 1) * 64, wcol = (wave & 1) * 64;
  int qd = lane >> 4, ln = lane & 15;

  f32x4 zero = {0.f, 0.f, 0.f, 0.f};
  f32x4 acc[4][4];
  for (int i = 0; i < 4; i++) for (int j = 0; j < 4; j++) acc[i][j] = zero;

  const u16* Ab = A  + (size_t)bm * 128 * K;
  const u16* Bb = Bm + (size_t)bn * 128 * K;

  for (int k0 = 0; k0 < K; k0 += 64) {
    __syncthreads();
    for (int j = 0; j < 4; j++) {
      int slot = (wave*4 + j)*64 + lane;
      int r = slot >> 3, kc = slot & 7;
      int c = (kc ^ (r & 7)) * 8;          // XOR swizzle (LDS dest is forced contiguous)
      async16(&Ab[(size_t)r * K + k0 + c], &As[(wave*4 + j) * 512]);
      async16(&Bb[(size_t)r * K + k0 + c], &Bs[(wave*4 + j) * 512]);
    }
    __syncthreads();
    for (int kk2 = 0; kk2 < 2; kk2++) {
      bf16x8 af[4], bfr[4];
      for (int mi = 0; mi < 4; mi++) {
        int row = wrow + mi*16 + ln;
        af[mi] = *(const bf16x8*)&As[(row*8 + ((kk2*4 + qd) ^ (ln & 7)))*8];
      }
      for (int ni = 0; ni < 4; ni++) {
        int row = wcol + ni*16 + ln;
        bfr[ni] = *(const bf16x8*)&Bs[(row*8 + ((kk2*4 + qd) ^ (ln & 7)))*8];
      }
      for (int mi = 0; mi < 4; mi++)
        for (int ni = 0; ni < 4; ni++)
          acc[mi][ni] = __builtin_amdgcn_mfma_f32_16x16x32_bf16(af[mi], bfr[ni], acc[mi][ni], 0, 0, 0);
    }
  }

  for (int ni = 0; ni < 4; ni++) {
    int nbase = bn*128 + wcol + ni*16 + ln;
    int three = nbase >> 10;        // wave-uniform
    int h = (nbase >> 6) & 15;
    int d = nbase & 63;
    float bv = bias[nbase];
    if (three == 2) {
      // V: [b,h,d,N] with XOR'd key chunks; 4 consecutive keys -> one 8B store
      for (int mi = 0; mi < 4; mi++) {
        int row0 = bm*128 + wrow + mi*16 + qd*4;
        int b = row0 >> 11, t0 = row0 & 2047;
        int chunkp = ((t0 >> 3) & 7) ^ (d & 7);
        u16 tmp[4];
        for (int r = 0; r < 4; r++) tmp[r] = f2bf(acc[mi][ni][r] + bv);
        size_t off = ((size_t)(b*H_ + h)*D_ + d)*N_TOK + (t0 >> 6)*64 + chunkp*8 + (t0 & 7);
        *(ushort4*)&vout[off] = *(ushort4*)tmp;
      }
    } else if (three == 1) {
      // K blocked, rows permuted by p(w)
      int c = d >> 3, e = d & 7;
      for (int mi = 0; mi < 4; mi++) {
        for (int r = 0; r < 4; r++) {
          int row = bm*128 + wrow + mi*16 + qd*4 + r;
          int b = row >> 11, t = row & 2047;
          int t32 = t >> 5, w = t & 31;
          int p = ((w >> 2) & 1)*16 + ((w >> 3) & 3)*4 + (w & 3);
          kout[((size_t)(b*H_ + h)*64 + t32)*2048 + (c*32 + p)*8 + e] = f2bf(acc[mi][ni][r] + bv);
        }
      }
    } else {
      float sc = 0.18033688011f;  // 0.125*log2(e) folded into Q
      for (int mi = 0; mi < 4; mi++) {
        for (int r = 0; r < 4; r++) {
          int row = bm*128 + wrow + mi*16 + qd*4 + r;
          int b = row >> 11, t = row & 2047;
          qout[(((size_t)(b*H_ + h))*N_TOK + t)*D_ + d] = f2bf((acc[mi][ni][r] + bv) * sc);
        }
      }
    }
  }
}

// ---------------- flash attention: round-0 schedule + T15 deferred-PV pipeline ----------------
// block = 4 waves x 32 q-rows = 128 rows; grid 512 (XCD-swizzled) -> 2 blocks/CU.
// Round-0 2-barrier/iter staging (measured best); PV(t-1) executes from REGISTERS
// (pk/vf held one tile deep) BETWEEN QK(t) and exp(t): independent MFMA work
// overlaps the exp2/pack VALU stream (T15 analog, m214v36 +7-11%).
// Ping-pong via macro-expanded named sets A/B (no runtime reg indexing).
__global__ __launch_bounds__(256, 2) void k_attn(
    const u16* __restrict__ Q, const u16* __restrict__ Kb, const u16* __restrict__ Vb,
    u16* __restrict__ Oa)   // [B*N][C] bf16
{
  __shared__ u16 Ks[4096];   // two 32-key tiles: [pair:2][c:8][row:32][e:8]
  __shared__ u16 Vs[4096];   // [d:64][chunk':8][e:8], chunk' = kc ^ (d&7)
  int ord = blockIdx.x;                 // 0..511
  int xcd = ord & 7, kk = ord >> 3;
  int bh = xcd * 4 + (kk & 3);          // 4 heads per XCD -> K/V L2-resident
  int qt = kk >> 2;                     // 0..15
  int b = bh >> 4, h = bh & 15;
  int tid = threadIdx.x, lane = tid & 63, wave = tid >> 6;
  int qd = lane >> 4, ln = lane & 15;

  const u16* Qg = Q  + ((size_t)bh * N_TOK + qt*128 + wave*32) * D_;
  const u16* Kg = Kb + (size_t)bh * 64 * 2048;
  const u16* Vg = Vb + (size_t)bh * (size_t)D_ * N_TOK;

  bf16x8 qf[2][2];
  for (int mi = 0; mi < 2; mi++)
    for (int ks = 0; ks < 2; ks++)
      qf[mi][ks] = *(const bf16x8*)&Qg[(mi*16 + ln)*D_ + ks*32 + qd*8];

  f32x4 z = {0.f, 0.f, 0.f, 0.f};
  f32x4 oacc[2][4];
  float lsum[2] = {0.f, 0.f};
  for (int mi = 0; mi < 2; mi++) for (int di = 0; di < 4; di++) oacc[mi][di] = z;

  bf16x8 vfA[4][2], vfB[4][2];   // V fragments, one tile deep
  bf16x8 pkA[2][2], pkB[2][2];   // packed P fragments, one tile deep

// One 64-key tile: stage -> load frags -> QK(KT) -> PV(KT-1, regs) -> exp/pack(KT).
// DOPREV is a literal 0/1; all loops fully unrolled, all indices compile-time.
#define ATTN_BODY(KT, vfC, pkC, vfP, pkP, DOPREV)                                \
  {                                                                              \
    __syncthreads();                                                             \
    {                                                                            \
      const u16* Kt = Kg + (size_t)(KT) * 4096;                                  \
      for (int j = 0; j < 2; j++) {                                              \
        int c0 = j*256 + wave*64;                                                \
        async16(&Kt[(c0 + lane)*8], &Ks[c0*8]);                                  \
        int cc = c0 + lane;                                                      \
        int dd = cc >> 3, kcp = cc & 7;                                          \
        async16(&Vg[(size_t)dd*N_TOK + (size_t)(KT)*64 + kcp*8], &Vs[c0*8]);     \
      }                                                                          \
    }                                                                            \
    __syncthreads();                                                             \
    bf16x8 kf[4][2];                                                             \
    for (int nt = 0; nt < 4; nt++)                                               \
      for (int ksd = 0; ksd < 2; ksd++)                                          \
        kf[nt][ksd] = *(const bf16x8*)&Ks[(nt>>1)*2048 + ((ksd*4 + qd)*32 + (nt&1)*16 + ln)*8]; \
    for (int di = 0; di < 4; di++)                                               \
      for (int hf = 0; hf < 2; hf++) {                                           \
        int dd = di*16 + ln;                                                     \
        vfC[di][hf] = *(const bf16x8*)&Vs[(dd*8 + ((hf*4 + qd) ^ (ln & 7)))*8];  \
      }                                                                          \
    f32x4 sacc[2][4];                                                            \
    for (int mi = 0; mi < 2; mi++)                                               \
      for (int nt = 0; nt < 4; nt++) {                                           \
        sacc[mi][nt] = z;                                                        \
        for (int ksd = 0; ksd < 2; ksd++)                                        \
          sacc[mi][nt] = __builtin_amdgcn_mfma_f32_16x16x32_bf16(kf[nt][ksd], qf[mi][ksd], sacc[mi][nt], 0, 0, 0); \
      }                                                                          \
    if (DOPREV) {                                                                \
      for (int mi = 0; mi < 2; mi++)                                             \
        for (int hf = 0; hf < 2; hf++)                                           \
          for (int di = 0; di < 4; di++)                                         \
            oacc[mi][di] = __builtin_amdgcn_mfma_f32_16x16x32_bf16(pkP[mi][hf], vfP[di][hf], oacc[mi][di], 0, 0, 0); \
    }                                                                            \
    for (int mi = 0; mi < 2; mi++)                                               \
      for (int hf = 0; hf < 2; hf++) {                                           \
        union { u16 s[8]; bf16x8 v; } pkt;                                       \
        for (int nth = 0; nth < 2; nth++)                                        \
          for (int i = 0; i < 4; i++) {                                          \
            float e = __builtin_amdgcn_exp2f(sacc[mi][(hf)*2 + nth][i]);         \
            lsum[mi] += e;                                                       \
            pkt.s[nth*4 + i] = f2bf_fast(e);                                     \
          }                                                                      \
        pkC[mi][hf] = pkt.v;                                                     \
      }                                                                          \
  }

  // peel tile 0 (no previous PV); tiles alternate A,B,A,... (tile 0 -> A)
  ATTN_BODY(0, vfA, pkA, vfB, pkB, 0)
  for (int kt = 1; kt < 31; kt += 2) {
    ATTN_BODY(kt,     vfB, pkB, vfA, pkA, 1)   // odd tile -> B, prev = A
    ATTN_BODY(kt + 1, vfA, pkA, vfB, pkB, 1)   // even tile -> A, prev = B
  }
  ATTN_BODY(31, vfB, pkB, vfA, pkA, 1)         // tile 31 -> B, prev = tile 30 (A)
  // epilogue: PV for tile 31 (held in B)
  for (int mi = 0; mi < 2; mi++)
    for (int hf = 0; hf < 2; hf++)
      for (int di = 0; di < 4; di++)
        oacc[mi][di] = __builtin_amdgcn_mfma_f32_16x16x32_bf16(pkB[mi][hf], vfB[di][hf], oacc[mi][di], 0, 0, 0);
#undef ATTN_BODY

  for (int mi = 0; mi < 2; mi++) {
    float ls = lsum[mi];
    ls += __shfl_xor(ls, 16, 64);
    ls += __shfl_xor(ls, 32, 64);
    float rl[4];
    for (int r = 0; r < 4; r++)
      rl[r] = 1.0f / __shfl(ls, qd*4 + r, 64);
    for (int di = 0; di < 4; di++)
      for (int r = 0; r < 4; r++) {
        int t = qt*128 + wave*32 + mi*16 + qd*4 + r;
        Oa[((size_t)b*N_TOK + t)*C_ + h*D_ + di*16 + ln] = f2bf(oacc[mi][di][r] * rl[r]);
      }
  }
}

// ---------------- GEMM2: out = attn @ w_out^T + b_out (fp32 out) ----------------
// 64x128 tile (grid 64x8=512 -> 2 blocks/CU), BK=64, XOR-swizzled staging/read
// (old linear layout was an 8-way ds_read bank conflict), double-buffered LDS,
// single barrier per K-step with issue-early staging.
__global__ __launch_bounds__(256, 2) void k_gemm_out(
    const u16* __restrict__ A, const u16* __restrict__ Bm,
    const float* __restrict__ bias, float* __restrict__ out)
{
  __shared__ u16 As[2][64*64];    // 8 KB x2
  __shared__ u16 Bs[2][128*64];   // 16 KB x2
  const int K = C_;
  int bm = blockIdx.x, bn = blockIdx.y;
  int tid = threadIdx.x;
  int lane = tid & 63, wave = tid >> 6;
  int wcol = wave * 32;
  int qd = lane >> 4, ln = lane & 15;

  f32x4 zero = {0.f, 0.f, 0.f, 0.f};
  f32x4 acc[4][2];
  for (int i = 0; i < 4; i++) for (int j = 0; j < 2; j++) acc[i][j] = zero;

  const u16* Ab = A  + (size_t)bm * 64 * K;
  const u16* Bb = Bm + (size_t)bn * 128 * K;

  auto stage = [&](int buf, int k0) {
    for (int j = 0; j < 2; j++) {            // A: 64x64 = 512 slots of 16B
      int slot = (wave*2 + j)*64 + lane;
      int r = slot >> 3, kc = slot & 7;
      int c = (kc ^ (r & 7)) * 8;            // XOR swizzle
      async16(&Ab[(size_t)r * K + k0 + c], &As[buf][(wave*2 + j) * 512]);
    }
    for (int j = 0; j < 4; j++) {            // B: 128x64 = 1024 slots
      int slot = (wave*4 + j)*64 + lane;
      int r = slot >> 3, kc = slot & 7;
      int c = (kc ^ (r & 7)) * 8;
      async16(&Bb[(size_t)r * K + k0 + c], &Bs[buf][(wave*4 + j) * 512]);
    }
  };

  stage(0, 0);
  __syncthreads();

  for (int t = 0; t < K/64; t++) {
    int cur = t & 1;
    if (t < K/64 - 1) stage(cur ^ 1, (t+1)*64);   // prefetch flies under MFMAs
    for (int kk2 = 0; kk2 < 2; kk2++) {
      bf16x8 af[4], bfr[2];
      for (int mi = 0; mi < 4; mi++) {
        int row = mi*16 + ln;
        af[mi] = *(const bf16x8*)&As[cur][(row*8 + ((kk2*4 + qd) ^ (ln & 7)))*8];
      }
      for (int ni = 0; ni < 2; ni++) {
        int row = wcol + ni*16 + ln;
        bfr[ni] = *(const bf16x8*)&Bs[cur][(row*8 + ((kk2*4 + qd) ^ (ln & 7)))*8];
      }
      for (int mi = 0; mi < 4; mi++)
        for (int ni = 0; ni < 2; ni++)
          acc[mi][ni] = __builtin_amdgcn_mfma_f32_16x16x32_bf16(af[mi], bfr[ni], acc[mi][ni], 0, 0, 0);
    }
    __syncthreads();
  }

  for (int ni = 0; ni < 2; ni++) {
    int col = bn*128 + wcol + ni*16 + ln;
    float bv = bias[col];
    for (int mi = 0; mi < 4; mi++)
      for (int r = 0; r < 4; r++) {
        int row = bm*64 + mi*16 + qd*4 + r;
        out[(size_t)row * C_ + col] = acc[mi][ni][r] + bv;
      }
  }
}

extern "C" void kernel_launch(void* const* d_in, const int* in_sizes, int n_in,
                              void* d_out, int out_size, void* d_ws, size_t ws_size,
                              hipStream_t stream) {
  const float* x     = (const float*)d_in[0];
  const float* w_qkv = (const float*)d_in[1];
  const float* b_qkv = (const float*)d_in[2];
  const float* w_out = (const float*)d_in[3];
  const float* b_out = (const float*)d_in[4];
  float* out = (float*)d_out;

  char* ws = (char*)d_ws;
  u16* x_bf    = (u16*)(ws);
  u16* wqkv_bf = (u16*)(ws + (size_t)8*1024*1024);
  u16* wout_bf = (u16*)(ws + (size_t)14*1024*1024);
  u16* q_bf    = (u16*)(ws + (size_t)16*1024*1024);  // [B,H,N,D], pre-scaled
  u16* k_bf    = (u16*)(ws + (size_t)24*1024*1024);  // blocked, rows permuted
  u16* v_bf    = (u16*)(ws + (size_t)32*1024*1024);  // [b,h,d,N], chunks XOR-swizzled
  u16* a_bf    = (u16*)(ws + (size_t)40*1024*1024);  // [M][C]

  k_cvt<<<8192, 256, 0, stream>>>(x, w_qkv, w_out, x_bf, wqkv_bf, wout_bf);
  k_gemm_qkv<<<dim3(32, 24), 256, 0, stream>>>(x_bf, wqkv_bf, b_qkv, q_bf, k_bf, v_bf);
  k_attn<<<512, 256, 0, stream>>>(q_bf, k_bf, v_bf, a_bf);
  k_gemm_out<<<dim3(64, 8), 256, 0, stream>>>(a_bf, wout_bf, b_out, out);
}

// Round 4
// 166.226 us; speedup vs baseline: 1.0419x; 1.0265x over previous
//
#include <hip/hip_runtime.h>

#define B_    2
#define N_TOK 2048
#define C_    1024
#define H_    16
#define D_    64
#define M_    (B_*N_TOK)   // 4096
#define N3C   3072

typedef unsigned short u16;
typedef unsigned int   u32;

typedef __attribute__((ext_vector_type(8))) short bf16x8;
typedef __attribute__((ext_vector_type(4))) float f32x4;

__device__ __forceinline__ u16 f2bf(float f) {       // RNE
  u32 u = __float_as_uint(f);
  return (u16)((u + 0x7FFFu + ((u >> 16) & 1u)) >> 16);
}

// packed fp32x2 -> bf16x2 (RNE), single VALU instr
__device__ __forceinline__ u32 cvtpk_bf16(float lo, float hi) {
  u32 r;
  asm("v_cvt_pk_bf16_f32 %0, %1, %2" : "=v"(r) : "v"(lo), "v"(hi));
  return r;
}

// async global->LDS, 16B/lane; LDS dest = wave-uniform base + lane*16
__device__ __forceinline__ void async16(const u16* g, u16* l) {
  __builtin_amdgcn_global_load_lds(
      (const __attribute__((address_space(1))) u32*)g,
      (__attribute__((address_space(3))) u32*)l, 16, 0, 0);
}

// ---------------- fused fp32 -> bf16 convert ----------------
__global__ void k_cvt(const float* __restrict__ x, const float* __restrict__ wq,
                      const float* __restrict__ wo,
                      u16* __restrict__ xb, u16* __restrict__ wqb, u16* __restrict__ wob) {
  size_t i = ((size_t)blockIdx.x * 256 + threadIdx.x) * 4;
  const size_t n0 = (size_t)M_ * C_;
  const size_t n1 = n0 + (size_t)N3C * C_;
  const float* s; u16* d;
  if (i < n0)      { s = x  + i;        d = xb  + i; }
  else if (i < n1) { s = wq + (i - n0); d = wqb + (i - n0); }
  else             { s = wo + (i - n1); d = wob + (i - n1); }
  float4 v = *(const float4*)s;
  *(ushort4*)d = make_ushort4(f2bf(v.x), f2bf(v.y), f2bf(v.z), f2bf(v.w));
}

// ---------------- GEMM1: qkv = x @ w_qkv^T + b   (BK=64, swizzled staging) ----------------
// Q -> [B,H,N,D] pre-scaled by 0.125*log2(e).
// K -> blocked [bh][t32:64][c:8][row:32][e:8], rows PERMUTED: key w at row
//      p(w) = ((w>>2)&1)*16 + ((w>>3)&3)*4 + (w&3)  (makes S^T C-layout == K=32 A-frag).
// V -> [b,h,d,N], key-chunks XOR-swizzled: chunk' = ((t>>3)&7) ^ (d&7).
__global__ __launch_bounds__(256, 3) void k_gemm_qkv(
    const u16* __restrict__ A, const u16* __restrict__ Bm,
    const float* __restrict__ bias,
    u16* __restrict__ qout, u16* __restrict__ kout, u16* __restrict__ vout)
{
  __shared__ u16 As[128*64];   // 16 KB
  __shared__ u16 Bs[128*64];   // 16 KB
  const int K = C_;
  int bm = blockIdx.x, bn = blockIdx.y;
  int tid = threadIdx.x;
  int lane = tid & 63, wave = tid >> 6;
  int wrow = (wave >> 1) * 64, wcol = (wave & 1) * 64;
  int qd = lane >> 4, ln = lane & 15;

  f32x4 zero = {0.f, 0.f, 0.f, 0.f};
  f32x4 acc[4][4];
  for (int i = 0; i < 4; i++) for (int j = 0; j < 4; j++) acc[i][j] = zero;

  const u16* Ab = A  + (size_t)bm * 128 * K;
  const u16* Bb = Bm + (size_t)bn * 128 * K;

  for (int k0 = 0; k0 < K; k0 += 64) {
    __syncthreads();
    for (int j = 0; j < 4; j++) {
      int slot = (wave*4 + j)*64 + lane;
      int r = slot >> 3, kc = slot & 7;
      int c = (kc ^ (r & 7)) * 8;          // XOR swizzle (LDS dest is forced contiguous)
      async16(&Ab[(size_t)r * K + k0 + c], &As[(wave*4 + j) * 512]);
      async16(&Bb[(size_t)r * K + k0 + c], &Bs[(wave*4 + j) * 512]);
    }
    __syncthreads();
    for (int kk2 = 0; kk2 < 2; kk2++) {
      bf16x8 af[4], bfr[4];
      for (int mi = 0; mi < 4; mi++) {
        int row = wrow + mi*16 + ln;
        af[mi] = *(const bf16x8*)&As[(row*8 + ((kk2*4 + qd) ^ (ln & 7)))*8];
      }
      for (int ni = 0; ni < 4; ni++) {
        int row = wcol + ni*16 + ln;
        bfr[ni] = *(const bf16x8*)&Bs[(row*8 + ((kk2*4 + qd) ^ (ln & 7)))*8];
      }
      for (int mi = 0; mi < 4; mi++)
        for (int ni = 0; ni < 4; ni++)
          acc[mi][ni] = __builtin_amdgcn_mfma_f32_16x16x32_bf16(af[mi], bfr[ni], acc[mi][ni], 0, 0, 0);
    }
  }

  for (int ni = 0; ni < 4; ni++) {
    int nbase = bn*128 + wcol + ni*16 + ln;
    int three = nbase >> 10;        // wave-uniform
    int h = (nbase >> 6) & 15;
    int d = nbase & 63;
    float bv = bias[nbase];
    if (three == 2) {
      // V: [b,h,d,N] with XOR'd key chunks; 4 consecutive keys -> one 8B store
      for (int mi = 0; mi < 4; mi++) {
        int row0 = bm*128 + wrow + mi*16 + qd*4;
        int b = row0 >> 11, t0 = row0 & 2047;
        int chunkp = ((t0 >> 3) & 7) ^ (d & 7);
        u16 tmp[4];
        for (int r = 0; r < 4; r++) tmp[r] = f2bf(acc[mi][ni][r] + bv);
        size_t off = ((size_t)(b*H_ + h)*D_ + d)*N_TOK + (t0 >> 6)*64 + chunkp*8 + (t0 & 7);
        *(ushort4*)&vout[off] = *(ushort4*)tmp;
      }
    } else if (three == 1) {
      // K blocked, rows permuted by p(w)
      int c = d >> 3, e = d & 7;
      for (int mi = 0; mi < 4; mi++) {
        for (int r = 0; r < 4; r++) {
          int row = bm*128 + wrow + mi*16 + qd*4 + r;
          int b = row >> 11, t = row & 2047;
          int t32 = t >> 5, w = t & 31;
          int p = ((w >> 2) & 1)*16 + ((w >> 3) & 3)*4 + (w & 3);
          kout[((size_t)(b*H_ + h)*64 + t32)*2048 + (c*32 + p)*8 + e] = f2bf(acc[mi][ni][r] + bv);
        }
      }
    } else {
      float sc = 0.18033688011f;  // 0.125*log2(e) folded into Q
      for (int mi = 0; mi < 4; mi++) {
        for (int r = 0; r < 4; r++) {
          int row = bm*128 + wrow + mi*16 + qd*4 + r;
          int b = row >> 11, t = row & 2047;
          qout[(((size_t)(b*H_ + h))*N_TOK + t)*D_ + d] = f2bf((acc[mi][ni][r] + bv) * sc);
        }
      }
    }
  }
}

// ---------------- flash attention: round-0 schedule, VALU-minimized softmax ----------------
// block = 4 waves x 32 q-rows = 128 rows; grid 512 (XCD-swizzled) -> 2 blocks/CU.
// VALU cuts vs round-0:
//  (1) row-sums via ones-column MFMA: sumacc = mfma(P, ones, sumacc) -- removes 64
//      serial lsum adds/tile AND the epilogue shuffle reduce (sum lands in oacc's
//      exact C-layout, so rl[r] = 1/sumacc[mi][r] directly).
//  (2) v_cvt_pk_bf16_f32 packs P pairs in 1 instr (replaces add+shift+merge chains).
__global__ __launch_bounds__(256, 2) void k_attn(
    const u16* __restrict__ Q, const u16* __restrict__ Kb, const u16* __restrict__ Vb,
    u16* __restrict__ Oa)   // [B*N][C] bf16
{
  __shared__ u16 Ks[4096];   // two 32-key tiles: [pair:2][c:8][row:32][e:8]
  __shared__ u16 Vs[4096];   // [d:64][chunk':8][e:8], chunk' = kc ^ (d&7)
  int ord = blockIdx.x;                 // 0..511
  int xcd = ord & 7, kk = ord >> 3;
  int bh = xcd * 4 + (kk & 3);          // 4 heads per XCD -> K/V L2-resident
  int qt = kk >> 2;                     // 0..15
  int b = bh >> 4, h = bh & 15;
  int tid = threadIdx.x, lane = tid & 63, wave = tid >> 6;
  int qd = lane >> 4, ln = lane & 15;

  const u16* Qg = Q  + ((size_t)bh * N_TOK + qt*128 + wave*32) * D_;
  const u16* Kg = Kb + (size_t)bh * 64 * 2048;
  const u16* Vg = Vb + (size_t)bh * (size_t)D_ * N_TOK;

  bf16x8 qf[2][2];
  for (int mi = 0; mi < 2; mi++)
    for (int ks = 0; ks < 2; ks++)
      qf[mi][ks] = *(const bf16x8*)&Qg[(mi*16 + ln)*D_ + ks*32 + qd*8];

  const short one_bf = (short)0x3F80;   // bf16 1.0
  bf16x8 ones = {one_bf, one_bf, one_bf, one_bf, one_bf, one_bf, one_bf, one_bf};

  f32x4 z = {0.f, 0.f, 0.f, 0.f};
  f32x4 oacc[2][4];
  f32x4 sumacc[2] = {z, z};             // P row-sums, same C-layout as oacc
  for (int mi = 0; mi < 2; mi++) for (int di = 0; di < 4; di++) oacc[mi][di] = z;

  for (int kt = 0; kt < 32; kt++) {     // 64 keys per iteration
    __syncthreads();
    const u16* Kt = Kg + (size_t)kt * 4096;   // two consecutive 32-key blocked tiles
    for (int j = 0; j < 2; j++) {
      int c0 = j*256 + wave*64;
      async16(&Kt[(c0 + lane)*8], &Ks[c0*8]);
      int cc = c0 + lane;
      int d = cc >> 3, kcp = cc & 7;          // LDS holds swizzled chunks as-is
      async16(&Vg[(size_t)d*N_TOK + kt*64 + kcp*8], &Vs[c0*8]);
    }
    __syncthreads();

    bf16x8 kf[4][2];
    for (int nt = 0; nt < 4; nt++)
      for (int ksd = 0; ksd < 2; ksd++)
        kf[nt][ksd] = *(const bf16x8*)&Ks[(nt>>1)*2048 + ((ksd*4 + qd)*32 + (nt&1)*16 + ln)*8];
    bf16x8 vf[4][2];
    for (int di = 0; di < 4; di++)
      for (int hf = 0; hf < 2; hf++) {
        int d = di*16 + ln;
        vf[di][hf] = *(const bf16x8*)&Vs[(d*8 + ((hf*4 + qd) ^ (ln & 7)))*8];
      }

    // S^T: rows = permuted key positions; sacc[mi][nt][r] at lane qd = key qd*8+(nt&1)*4+r of half nt>>1
    f32x4 sacc[2][4];
    for (int mi = 0; mi < 2; mi++)
      for (int nt = 0; nt < 4; nt++) {
        sacc[mi][nt] = z;
        for (int ksd = 0; ksd < 2; ksd++)
          sacc[mi][nt] = __builtin_amdgcn_mfma_f32_16x16x32_bf16(kf[nt][ksd], qf[mi][ksd], sacc[mi][nt], 0, 0, 0);
      }

    // P = exp2(S'); pack pairs with v_cvt_pk_bf16_f32; row-sum via ones-MFMA
    for (int mi = 0; mi < 2; mi++)
      for (int hf = 0; hf < 2; hf++) {
        union { u32 w[4]; bf16x8 v; } pk;
        pk.w[0] = cvtpk_bf16(__builtin_amdgcn_exp2f(sacc[mi][hf*2 + 0][0]),
                             __builtin_amdgcn_exp2f(sacc[mi][hf*2 + 0][1]));
        pk.w[1] = cvtpk_bf16(__builtin_amdgcn_exp2f(sacc[mi][hf*2 + 0][2]),
                             __builtin_amdgcn_exp2f(sacc[mi][hf*2 + 0][3]));
        pk.w[2] = cvtpk_bf16(__builtin_amdgcn_exp2f(sacc[mi][hf*2 + 1][0]),
                             __builtin_amdgcn_exp2f(sacc[mi][hf*2 + 1][1]));
        pk.w[3] = cvtpk_bf16(__builtin_amdgcn_exp2f(sacc[mi][hf*2 + 1][2]),
                             __builtin_amdgcn_exp2f(sacc[mi][hf*2 + 1][3]));
        sumacc[mi] = __builtin_amdgcn_mfma_f32_16x16x32_bf16(pk.v, ones, sumacc[mi], 0, 0, 0);
        for (int di = 0; di < 4; di++)
          oacc[mi][di] = __builtin_amdgcn_mfma_f32_16x16x32_bf16(pk.v, vf[di][hf], oacc[mi][di], 0, 0, 0);
      }
  }

  for (int mi = 0; mi < 2; mi++) {
    float rl[4];
    for (int r = 0; r < 4; r++)
      rl[r] = 1.0f / sumacc[mi][r];     // row-sum already in matching C-layout
    for (int di = 0; di < 4; di++)
      for (int r = 0; r < 4; r++) {
        int t = qt*128 + wave*32 + mi*16 + qd*4 + r;
        Oa[((size_t)b*N_TOK + t)*C_ + h*D_ + di*16 + ln] = f2bf(oacc[mi][di][r] * rl[r]);
      }
  }
}

// ---------------- GEMM2: out = attn @ w_out^T + b_out (fp32 out) ----------------
// 64x128 tile (grid 64x8=512 -> 2 blocks/CU), BK=64, XOR-swizzled staging/read
// (old linear layout was an 8-way ds_read bank conflict), double-buffered LDS,
// single barrier per K-step with issue-early staging.
__global__ __launch_bounds__(256, 2) void k_gemm_out(
    const u16* __restrict__ A, const u16* __restrict__ Bm,
    const float* __restrict__ bias, float* __restrict__ out)
{
  __shared__ u16 As[2][64*64];    // 8 KB x2
  __shared__ u16 Bs[2][128*64];   // 16 KB x2
  const int K = C_;
  int bm = blockIdx.x, bn = blockIdx.y;
  int tid = threadIdx.x;
  int lane = tid & 63, wave = tid >> 6;
  int wcol = wave * 32;
  int qd = lane >> 4, ln = lane & 15;

  f32x4 zero = {0.f, 0.f, 0.f, 0.f};
  f32x4 acc[4][2];
  for (int i = 0; i < 4; i++) for (int j = 0; j < 2; j++) acc[i][j] = zero;

  const u16* Ab = A  + (size_t)bm * 64 * K;
  const u16* Bb = Bm + (size_t)bn * 128 * K;

  auto stage = [&](int buf, int k0) {
    for (int j = 0; j < 2; j++) {            // A: 64x64 = 512 slots of 16B
      int slot = (wave*2 + j)*64 + lane;
      int r = slot >> 3, kc = slot & 7;
      int c = (kc ^ (r & 7)) * 8;            // XOR swizzle
      async16(&Ab[(size_t)r * K + k0 + c], &As[buf][(wave*2 + j) * 512]);
    }
    for (int j = 0; j < 4; j++) {            // B: 128x64 = 1024 slots
      int slot = (wave*4 + j)*64 + lane;
      int r = slot >> 3, kc = slot & 7;
      int c = (kc ^ (r & 7)) * 8;
      async16(&Bb[(size_t)r * K + k0 + c], &Bs[buf][(wave*4 + j) * 512]);
    }
  };

  stage(0, 0);
  __syncthreads();

  for (int t = 0; t < K/64; t++) {
    int cur = t & 1;
    if (t < K/64 - 1) stage(cur ^ 1, (t+1)*64);   // prefetch flies under MFMAs
    for (int kk2 = 0; kk2 < 2; kk2++) {
      bf16x8 af[4], bfr[2];
      for (int mi = 0; mi < 4; mi++) {
        int row = mi*16 + ln;
        af[mi] = *(const bf16x8*)&As[cur][(row*8 + ((kk2*4 + qd) ^ (ln & 7)))*8];
      }
      for (int ni = 0; ni < 2; ni++) {
        int row = wcol + ni*16 + ln;
        bfr[ni] = *(const bf16x8*)&Bs[cur][(row*8 + ((kk2*4 + qd) ^ (ln & 7)))*8];
      }
      for (int mi = 0; mi < 4; mi++)
        for (int ni = 0; ni < 2; ni++)
          acc[mi][ni] = __builtin_amdgcn_mfma_f32_16x16x32_bf16(af[mi], bfr[ni], acc[mi][ni], 0, 0, 0);
    }
    __syncthreads();
  }

  for (int ni = 0; ni < 2; ni++) {
    int col = bn*128 + wcol + ni*16 + ln;
    float bv = bias[col];
    for (int mi = 0; mi < 4; mi++)
      for (int r = 0; r < 4; r++) {
        int row = bm*64 + mi*16 + qd*4 + r;
        out[(size_t)row * C_ + col] = acc[mi][ni][r] + bv;
      }
  }
}

extern "C" void kernel_launch(void* const* d_in, const int* in_sizes, int n_in,
                              void* d_out, int out_size, void* d_ws, size_t ws_size,
                              hipStream_t stream) {
  const float* x     = (const float*)d_in[0];
  const float* w_qkv = (const float*)d_in[1];
  const float* b_qkv = (const float*)d_in[2];
  const float* w_out = (const float*)d_in[3];
  const float* b_out = (const float*)d_in[4];
  float* out = (float*)d_out;

  char* ws = (char*)d_ws;
  u16* x_bf    = (u16*)(ws);
  u16* wqkv_bf = (u16*)(ws + (size_t)8*1024*1024);
  u16* wout_bf = (u16*)(ws + (size_t)14*1024*1024);
  u16* q_bf    = (u16*)(ws + (size_t)16*1024*1024);  // [B,H,N,D], pre-scaled
  u16* k_bf    = (u16*)(ws + (size_t)24*1024*1024);  // blocked, rows permuted
  u16* v_bf    = (u16*)(ws + (size_t)32*1024*1024);  // [b,h,d,N], chunks XOR-swizzled
  u16* a_bf    = (u16*)(ws + (size_t)40*1024*1024);  // [M][C]

  k_cvt<<<8192, 256, 0, stream>>>(x, w_qkv, w_out, x_bf, wqkv_bf, wout_bf);
  k_gemm_qkv<<<dim3(32, 24), 256, 0, stream>>>(x_bf, wqkv_bf, b_qkv, q_bf, k_bf, v_bf);
  k_attn<<<512, 256, 0, stream>>>(q_bf, k_bf, v_bf, a_bf);
  k_gemm_out<<<dim3(64, 8), 256, 0, stream>>>(a_bf, wout_bf, b_out, out);
}